// Round 4
// baseline (787.297 us; speedup 1.0000x reference)
//
#include <hip/hip_runtime.h>

// HNM discriminative loss, MI355X — R7.
// predict (4,32,512,1024) f32, target (4,512,1024) i32 -> scalar f32.
// R7: R6 killed the LDS same-address-atomic drain (conflicts 77824->0,
// k_accum 357->213us, VALU 0.57->41%). Remaining k_accum cost is the
// mask-FMA binning itself: 57 VALU lane-ops/element (~46us pure + 24%
// occupancy + ch==0 stragglers -> 213us). Fix: per-THREAD private LDS
// histogram (stride 21, odd -> bank permutation, zero same-address
// collisions): 1 ds_add_f32 + 2 VALU per element. Counts get 32 dedicated
// blocks (grid 1056) instead of doubling ch==0 blocks' work.
// k_var / k_reduce / k_final byte-identical to R6 (single variable).

#define K_CLS 19
#define C_CH 32
#define HW_SHIFT 19            // H*W = 512*1024 = 2^19
#define HW_SIZE (1 << HW_SHIFT)
#define EPSF 1e-12f
#define THEA_F 0.5f
#define TWO_DELTA 3.0f
#define MIN_PIX 20.0f
#define HIST_STRIDE 21         // odd: lane*21 mod 32 is a bank permutation

// ---- ws float layout (no global atomics; every cell written before read) --
#define OFF_PSUM 0                       // [ch][32 slots][20] = 20480
#define OFF_PCNT 20480                   // [32 slots][20] = 640
#define OFF_RED  21120                   // 608 sums + 19 counts (pad 640)
#define OFF_VPART 21760                  // [1024 blk][64]: 19 sq + 19 pos
#define WS_FLOATS (OFF_VPART + 1024 * 64)

typedef const unsigned int __attribute__((address_space(1)))* GP;
typedef unsigned int __attribute__((address_space(3)))* LP;

__device__ __forceinline__ void atomAddF(float* p, float v) {
  unsafeAtomicAdd(p, v);       // LDS: ds_add_f32 (no return)
}

// ---- Pass 1 v4: private-histogram binning --------------------------------
// Blocks 0..1023: (plane,slab) feature sums. Blocks 1024..1055: counts.
// Each thread owns 21 LDS words; per element: min + addr + ds_add_f32.
__global__ __launch_bounds__(256) void k_accum(
    const float* __restrict__ pred, const int* __restrict__ tgt,
    float* __restrict__ ws)
{
  __shared__ float s_hist[256 * HIST_STRIDE];   // 21504 B
  __shared__ float s_w[4][20];
  const int t = threadIdx.x;
  const int w = t >> 6;
  float* hb = &s_hist[t * HIST_STRIDE];
#pragma unroll
  for (int k = 0; k < HIST_STRIDE; ++k) hb[k] = 0.f;
  // no barrier needed: histogram is thread-private until the flush

  if (blockIdx.x < 1024) {
    // ---- feature-sum block ----
    const int plane = blockIdx.x >> 3;       // n*32+ch
    const int slab  = blockIdx.x & 7;
    const int n_idx = plane >> 5;
    const int ch    = plane & 31;
    const float* pbase = pred + (((size_t)plane) << HW_SHIFT) + ((size_t)slab << 16);
    const int*   tbase = tgt  + (((size_t)n_idx) << HW_SHIFT) + ((size_t)slab << 16);

    float4 vA = *reinterpret_cast<const float4*>(pbase + t * 4);
    int4   cA = *reinterpret_cast<const int4*>(tbase + t * 4);
#pragma unroll 1
    for (int it = 0; it < 64; ++it) {
      float4 vB; int4 cB;
      if (it + 1 < 64) {
        vB = *reinterpret_cast<const float4*>(pbase + (it + 1) * 1024 + t * 4);
        cB = *reinterpret_cast<const int4*>(tbase + (it + 1) * 1024 + t * 4);
      }
      const float x[4] = {vA.x, vA.y, vA.z, vA.w};
      const int   s[4] = {cA.x, cA.y, cA.z, cA.w};
#pragma unroll
      for (int i = 0; i < 4; ++i) {
        const int slot = min((unsigned)s[i], (unsigned)K_CLS);  // 255 -> junk slot 19
        atomAddF(&hb[slot], x[i]);
      }
      vA = vB; cA = cB;
    }

    // flush: own 19 -> regs -> wave shfl reduce -> 4-wave combine -> ws
    float acc[K_CLS];
#pragma unroll
    for (int k = 0; k < K_CLS; ++k) acc[k] = hb[k];
#pragma unroll
    for (int k = 0; k < K_CLS; ++k) {
      float s = acc[k];
#pragma unroll
      for (int m = 1; m < 64; m <<= 1) s += __shfl_xor(s, m, 64);
      acc[k] = s;
    }
#pragma unroll
    for (int k = 0; k < K_CLS; ++k)
      if ((t & 63) == k) s_w[w][k] = acc[k];   // static index: no scratch
    __syncthreads();
    if (t < K_CLS) {
      const int slot = n_idx * 8 + slab;
      ws[OFF_PSUM + ch * 640 + slot * 20 + t] =
          s_w[0][t] + s_w[1][t] + s_w[2][t] + s_w[3][t];
    }
  } else {
    // ---- count block (reads tgt only) ----
    const int idx = blockIdx.x - 1024;       // 0..31
    const int n_idx = idx >> 3;
    const int slab  = idx & 7;
    const int* tbase = tgt + (((size_t)n_idx) << HW_SHIFT) + ((size_t)slab << 16);

#pragma unroll 1
    for (int it = 0; it < 64; ++it) {
      const int4 c4 = *reinterpret_cast<const int4*>(tbase + it * 1024 + t * 4);
      const int s[4] = {c4.x, c4.y, c4.z, c4.w};
#pragma unroll
      for (int i = 0; i < 4; ++i) {
        const int slot = min((unsigned)s[i], (unsigned)K_CLS);
        atomAddF(&hb[slot], 1.f);
      }
    }

    float acc[K_CLS];
#pragma unroll
    for (int k = 0; k < K_CLS; ++k) acc[k] = hb[k];
#pragma unroll
    for (int k = 0; k < K_CLS; ++k) {
      float s = acc[k];
#pragma unroll
      for (int m = 1; m < 64; m <<= 1) s += __shfl_xor(s, m, 64);
      acc[k] = s;
    }
#pragma unroll
    for (int k = 0; k < K_CLS; ++k)
      if ((t & 63) == k) s_w[w][k] = acc[k];
    __syncthreads();
    if (t < K_CLS) {
      const int slot = n_idx * 8 + slab;
      ws[OFF_PCNT + slot * 20 + t] = s_w[0][t] + s_w[1][t] + s_w[2][t] + s_w[3][t];
    }
  }
}

// ---- Reduce 32 slots -> 627 totals (single small block) -------------------
__global__ __launch_bounds__(256) void k_reduce(float* __restrict__ ws)
{
  const int t = threadIdx.x;
  for (int o = t; o < C_CH * K_CLS; o += 256) {
    const int ch = o / K_CLS, k = o - ch * K_CLS;
    float a = 0.f;
#pragma unroll 4
    for (int s = 0; s < 32; ++s) a += ws[OFF_PSUM + ch * 640 + s * 20 + k];
    ws[OFF_RED + o] = a;
  }
  if (t < K_CLS) {
    float a = 0.f;
#pragma unroll 4
    for (int s = 0; s < 32; ++s) a += ws[OFF_PCNT + s * 20 + t];
    ws[OFF_RED + C_CH * K_CLS + t] = a;
  }
}

// ---- Pass 2 v3: global_load_lds staged, px-per-lane windows (unchanged) ---
__global__ __launch_bounds__(256) void k_var(
    const float* __restrict__ pred, const int* __restrict__ tgt,
    float* __restrict__ ws)
{
  __shared__ float s_buf[4][2][C_CH][64];   // 64 KB
  __shared__ int   s_cls[4][2][256];        // 8 KB (only first 64 ints used)
  __shared__ float s_ctr[C_CH][K_CLS];
  __shared__ float s_sq[K_CLS];
  __shared__ float s_pos[K_CLS];

  const int t = threadIdx.x;
  const int w = t >> 6;
  const int lane = t & 63;

  for (int i = t; i < C_CH * K_CLS; i += 256) {
    const int k = i % K_CLS;
    (&s_ctr[0][0])[i] = ws[OFF_RED + i] / fmaxf(ws[OFF_RED + C_CH * K_CLS + k], 1.f);
  }
  if (t < K_CLS) { s_sq[t] = 0.f; s_pos[t] = 0.f; }
  __syncthreads();

  const size_t P0 = (size_t)blockIdx.x * 2048;
  const int n_idx = (int)(P0 >> HW_SHIFT);
  const int hw0 = (int)(P0 & (HW_SIZE - 1));
  const int qch = lane >> 4;
  const int qpx = (lane & 15) * 4;

#define STAGE(h, j)                                                           \
  {                                                                           \
    const int pw = hw0 + w * 512 + (j) * 64;                                  \
    _Pragma("unroll")                                                         \
    for (int q = 0; q < 8; ++q) {                                             \
      const int c = q * 4 + qch;                                              \
      const float* gp = pred + (((size_t)(n_idx * C_CH + c)) << HW_SHIFT)     \
                        + pw + qpx;                                           \
      __builtin_amdgcn_global_load_lds((GP)gp, (LP)&s_buf[w][h][0][0] + q * 256, \
                                       16, 0, 0);                             \
    }                                                                         \
    const int* gt = tgt + (((size_t)n_idx) << HW_SHIFT) + pw + qpx;           \
    __builtin_amdgcn_global_load_lds((GP)gt, (LP)&s_cls[w][h][0], 16, 0, 0);  \
  }

  float res8[8];
  int   cls8[8];

  STAGE(0, 0)
#pragma unroll 1
  for (int j = 0; j < 8; ++j) {
    const int h = j & 1;
    if (j < 7) {
      STAGE(h ^ 1, j + 1)
      asm volatile("s_waitcnt vmcnt(9)" ::: "memory");
    } else {
      asm volatile("s_waitcnt vmcnt(0)" ::: "memory");
    }
    __builtin_amdgcn_sched_barrier(0);

    const int ci = s_cls[w][h][lane];
    const bool vld = (unsigned)ci < K_CLS;
    const int sc = vld ? ci : 0;
    float d2 = 0.f;
#pragma unroll
    for (int c = 0; c < C_CH; ++c) {
      const float x = s_buf[w][h][c][lane];
      const float d = s_ctr[c][sc] - x;
      d2 = fmaf(d, d, d2);
    }
    res8[j] = d2;
    cls8[j] = vld ? ci : -1;
  }

#pragma unroll
  for (int j = 0; j < 8; ++j) {
    if (cls8[j] >= 0) {
      const float r = sqrtf(res8[j] + EPSF) - THEA_F;
      if (r > 0.f) { atomAddF(&s_sq[cls8[j]], r * r); atomAddF(&s_pos[cls8[j]], 1.f); }
    }
  }

  __syncthreads();
  if (t < K_CLS) {
    float* vp = ws + OFF_VPART + (size_t)blockIdx.x * 64;
    vp[t]         = s_sq[t];
    vp[K_CLS + t] = s_pos[t];
  }
#undef STAGE
}

// ---- Finalize: reduce vparts, then loss_var + loss_dis + 0.001*loss_reg ---
__global__ __launch_bounds__(1024) void k_final(
    float* __restrict__ ws, float* __restrict__ out, int nb)
{
  __shared__ float s_ctr[C_CH * K_CLS];
  __shared__ float s_valid[K_CLS];
  __shared__ float s_sq[K_CLS];
  __shared__ float s_pos[K_CLS];
  __shared__ float s_red[3];
  __shared__ float s_ncls;
  const int t = threadIdx.x;
  if (t < 3) s_red[t] = 0.f;
  if (t < K_CLS) { s_sq[t] = 0.f; s_pos[t] = 0.f; }
  if (t < K_CLS) s_valid[t] = (ws[OFF_RED + C_CH * K_CLS + t] > MIN_PIX) ? 1.f : 0.f;
  for (int i = t; i < C_CH * K_CLS; i += 1024) {
    const int k = i % K_CLS;
    s_ctr[i] = ws[OFF_RED + i] / fmaxf(ws[OFF_RED + C_CH * K_CLS + k], 1.f);
  }
  __syncthreads();

  {
    const int o = t & 63, slice = t >> 6;
    if (o < 2 * K_CLS) {
      float a = 0.f;
      for (int b = slice; b < nb; b += 16)
        a += ws[OFF_VPART + (size_t)b * 64 + o];
      atomAddF(o < K_CLS ? &s_sq[o] : &s_pos[o - K_CLS], a);
    }
  }
  __syncthreads();

  if (t == 0) {
    float n = 0.f;
    for (int k = 0; k < K_CLS; ++k) n += s_valid[k];
    s_ncls = fmaxf(n, 1.f);
  }
  if (t < K_CLS && s_valid[t] > 0.f) {
    atomAddF(&s_red[0], s_sq[t] / fmaxf(s_pos[t], 1.f));
    float nn = 0.f;
#pragma unroll
    for (int ch = 0; ch < C_CH; ++ch) {
      const float cv = s_ctr[ch * K_CLS + t];
      nn = fmaf(cv, cv, nn);
    }
    atomAddF(&s_red[2], sqrtf(nn + EPSF));
  }
  if (t < K_CLS * K_CLS) {
    const int a = t / K_CLS, b = t - (t / K_CLS) * K_CLS;
    if (a != b && s_valid[a] > 0.f && s_valid[b] > 0.f) {
      float dd = 0.f;
#pragma unroll
      for (int ch = 0; ch < C_CH; ++ch) {
        const float df = s_ctr[ch * K_CLS + a] - s_ctr[ch * K_CLS + b];
        dd = fmaf(df, df, dd);
      }
      const float dist = sqrtf(dd + EPSF);
      const float d = fmaxf(TWO_DELTA - dist, 0.f);
      if (d > 0.f) atomAddF(&s_red[1], d * d);
    }
  }
  __syncthreads();
  if (t == 0) {
    const float n = s_ncls;
    out[0] = s_red[0] / n
           + s_red[1] / fmaxf(n * (n - 1.f), 1.f)
           + 0.001f * s_red[2] / n;
  }
}

extern "C" void kernel_launch(void* const* d_in, const int* in_sizes, int n_in,
                              void* d_out, int out_size, void* d_ws, size_t ws_size,
                              hipStream_t stream) {
  const float* pred = (const float*)d_in[0];
  const int*   tgt  = (const int*)d_in[1];
  float* ws  = (float*)d_ws;
  float* out = (float*)d_out;
  const int P = in_sizes[1];            // n*h*w = 2097152
  const int nBlocksVar = P / 2048;      // 1024

  k_accum <<<1024 + 32, 256, 0, stream>>>(pred, tgt, ws);  // 1024 sum + 32 count
  k_reduce<<<1, 256, 0, stream>>>(ws);
  k_var   <<<nBlocksVar, 256, 0, stream>>>(pred, tgt, ws);
  k_final <<<1, 1024, 0, stream>>>(ws, out, nBlocksVar);
}

// Round 5
// 498.226 us; speedup vs baseline: 1.5802x; 1.5802x over previous
//
#include <hip/hip_runtime.h>

// HNM discriminative loss, MI355X — R8.
// predict (4,32,512,1024) f32, target (4,512,1024) i32 -> scalar f32.
// R8: R7 isolated a HW constant — LDS ATOMICS serialize lanes (~2.7 cy/lane,
// 170 cy/wave-op, conflicts 0, VALU 1.7%, 429us). R1-R6's "conflict drain"
// was mostly this. Plain ds_read/ds_write are bank-parallel (~6 cy/wave-op).
// Fix: keep per-THREAD private histogram, replace ds_add_f32 with plain
// RMW (read+v_add+write). DS budget/CU ~25-31us, HBM floor ~43us ->
// k_accum predicted 55-90us. Grid 2048+64 (32K-px slabs): 7 blocks/CU
// (21.5KB LDS), ~87% occupancy to hide the per-thread RAW chain latency.
// k_var / k_final unchanged from R6 (best known); k_reduce: 64 slots.

#define K_CLS 19
#define C_CH 32
#define HW_SHIFT 19            // H*W = 512*1024 = 2^19
#define HW_SIZE (1 << HW_SHIFT)
#define EPSF 1e-12f
#define THEA_F 0.5f
#define TWO_DELTA 3.0f
#define MIN_PIX 20.0f
#define HIST_STRIDE 21         // odd: lane*21 mod 32 permutes banks

// ---- ws float layout (no global atomics; every cell written before read) --
#define OFF_PSUM 0                       // [ch][64 slots][20] = 40960
#define OFF_PCNT 40960                   // [64 slots][20] = 1280
#define OFF_RED  42240                   // 608 sums + 19 counts (pad 640)
#define OFF_VPART 42880                  // [1024 blk][64]: 19 sq + 19 pos
#define WS_FLOATS (OFF_VPART + 1024 * 64)

typedef const unsigned int __attribute__((address_space(1)))* GP;
typedef unsigned int __attribute__((address_space(3)))* LP;

__device__ __forceinline__ void atomAddF(float* p, float v) {
  unsafeAtomicAdd(p, v);       // cold paths only (k_var flush, k_final)
}

// ---- Pass 1 v5: private-histogram binning, plain DS RMW ------------------
// Blocks 0..2047: (plane, 16 slabs) feature sums. Blocks 2048..2111: counts.
__global__ __launch_bounds__(256) void k_accum(
    const float* __restrict__ pred, const int* __restrict__ tgt,
    float* __restrict__ ws)
{
  __shared__ float s_hist[256 * HIST_STRIDE];   // 21504 B -> 7 blocks/CU
  __shared__ float s_w[4][20];
  const int t = threadIdx.x;
  const int w = t >> 6;
  float* hb = &s_hist[t * HIST_STRIDE];
#pragma unroll
  for (int k = 0; k < HIST_STRIDE; ++k) hb[k] = 0.f;
  // thread-private until flush: no barrier needed here

  if (blockIdx.x < 2048) {
    // ---- feature-sum block: plane = n*32+ch, slab = 32K px ----
    const int plane = blockIdx.x >> 4;       // 0..127
    const int slab  = blockIdx.x & 15;       // 0..15
    const int n_idx = plane >> 5;
    const int ch    = plane & 31;
    const float* pbase = pred + (((size_t)plane) << HW_SHIFT) + ((size_t)slab << 15);
    const int*   tbase = tgt  + (((size_t)n_idx) << HW_SHIFT) + ((size_t)slab << 15);

    float4 vA = *reinterpret_cast<const float4*>(pbase + t * 4);
    int4   cA = *reinterpret_cast<const int4*>(tbase + t * 4);
#pragma unroll 1
    for (int it = 0; it < 32; ++it) {
      float4 vB; int4 cB;
      if (it + 1 < 32) {
        vB = *reinterpret_cast<const float4*>(pbase + (it + 1) * 1024 + t * 4);
        cB = *reinterpret_cast<const int4*>(tbase + (it + 1) * 1024 + t * 4);
      }
      const float x[4] = {vA.x, vA.y, vA.z, vA.w};
      const int   s[4] = {cA.x, cA.y, cA.z, cA.w};
#pragma unroll
      for (int i = 0; i < 4; ++i) {
        const int slot = min((unsigned)s[i], (unsigned)K_CLS);  // 255 -> junk 19
        hb[slot] += x[i];                  // plain ds_read + v_add + ds_write
      }
      vA = vB; cA = cB;
    }

    // flush: own 19 bins -> regs -> wave shfl reduce -> 4-wave combine -> ws
    float acc[K_CLS];
#pragma unroll
    for (int k = 0; k < K_CLS; ++k) acc[k] = hb[k];
#pragma unroll
    for (int k = 0; k < K_CLS; ++k) {
      float s = acc[k];
#pragma unroll
      for (int m = 1; m < 64; m <<= 1) s += __shfl_xor(s, m, 64);
      acc[k] = s;
    }
#pragma unroll
    for (int k = 0; k < K_CLS; ++k)
      if ((t & 63) == k) s_w[w][k] = acc[k];   // static index: no scratch
    __syncthreads();
    if (t < K_CLS) {
      const int slot = n_idx * 16 + slab;      // 0..63
      ws[OFF_PSUM + ch * (64 * 20) + slot * 20 + t] =
          s_w[0][t] + s_w[1][t] + s_w[2][t] + s_w[3][t];
    }
  } else {
    // ---- count block (reads tgt only) ----
    const int idx = blockIdx.x - 2048;       // 0..63
    const int n_idx = idx >> 4;
    const int slab  = idx & 15;
    const int* tbase = tgt + (((size_t)n_idx) << HW_SHIFT) + ((size_t)slab << 15);

#pragma unroll 1
    for (int it = 0; it < 32; ++it) {
      const int4 c4 = *reinterpret_cast<const int4*>(tbase + it * 1024 + t * 4);
      const int s[4] = {c4.x, c4.y, c4.z, c4.w};
#pragma unroll
      for (int i = 0; i < 4; ++i) {
        const int slot = min((unsigned)s[i], (unsigned)K_CLS);
        hb[slot] += 1.f;
      }
    }

    float acc[K_CLS];
#pragma unroll
    for (int k = 0; k < K_CLS; ++k) acc[k] = hb[k];
#pragma unroll
    for (int k = 0; k < K_CLS; ++k) {
      float s = acc[k];
#pragma unroll
      for (int m = 1; m < 64; m <<= 1) s += __shfl_xor(s, m, 64);
      acc[k] = s;
    }
#pragma unroll
    for (int k = 0; k < K_CLS; ++k)
      if ((t & 63) == k) s_w[w][k] = acc[k];
    __syncthreads();
    if (t < K_CLS) {
      const int slot = n_idx * 16 + slab;
      ws[OFF_PCNT + slot * 20 + t] = s_w[0][t] + s_w[1][t] + s_w[2][t] + s_w[3][t];
    }
  }
}

// ---- Reduce 64 slots -> 627 totals (single small block) -------------------
__global__ __launch_bounds__(256) void k_reduce(float* __restrict__ ws)
{
  const int t = threadIdx.x;
  for (int o = t; o < C_CH * K_CLS; o += 256) {
    const int ch = o / K_CLS, k = o - ch * K_CLS;
    float a = 0.f;
#pragma unroll 4
    for (int s = 0; s < 64; ++s) a += ws[OFF_PSUM + ch * (64 * 20) + s * 20 + k];
    ws[OFF_RED + o] = a;
  }
  if (t < K_CLS) {
    float a = 0.f;
#pragma unroll 4
    for (int s = 0; s < 64; ++s) a += ws[OFF_PCNT + s * 20 + t];
    ws[OFF_RED + C_CH * K_CLS + t] = a;
  }
}

// ---- Pass 2 v3: global_load_lds staged, px-per-lane windows (unchanged) ---
__global__ __launch_bounds__(256) void k_var(
    const float* __restrict__ pred, const int* __restrict__ tgt,
    float* __restrict__ ws)
{
  __shared__ float s_buf[4][2][C_CH][64];   // 64 KB
  __shared__ int   s_cls[4][2][256];        // 8 KB (only first 64 ints used)
  __shared__ float s_ctr[C_CH][K_CLS];
  __shared__ float s_sq[K_CLS];
  __shared__ float s_pos[K_CLS];

  const int t = threadIdx.x;
  const int w = t >> 6;
  const int lane = t & 63;

  for (int i = t; i < C_CH * K_CLS; i += 256) {
    const int k = i % K_CLS;
    (&s_ctr[0][0])[i] = ws[OFF_RED + i] / fmaxf(ws[OFF_RED + C_CH * K_CLS + k], 1.f);
  }
  if (t < K_CLS) { s_sq[t] = 0.f; s_pos[t] = 0.f; }
  __syncthreads();

  const size_t P0 = (size_t)blockIdx.x * 2048;
  const int n_idx = (int)(P0 >> HW_SHIFT);
  const int hw0 = (int)(P0 & (HW_SIZE - 1));
  const int qch = lane >> 4;
  const int qpx = (lane & 15) * 4;

#define STAGE(h, j)                                                           \
  {                                                                           \
    const int pw = hw0 + w * 512 + (j) * 64;                                  \
    _Pragma("unroll")                                                         \
    for (int q = 0; q < 8; ++q) {                                             \
      const int c = q * 4 + qch;                                              \
      const float* gp = pred + (((size_t)(n_idx * C_CH + c)) << HW_SHIFT)     \
                        + pw + qpx;                                           \
      __builtin_amdgcn_global_load_lds((GP)gp, (LP)&s_buf[w][h][0][0] + q * 256, \
                                       16, 0, 0);                             \
    }                                                                         \
    const int* gt = tgt + (((size_t)n_idx) << HW_SHIFT) + pw + qpx;           \
    __builtin_amdgcn_global_load_lds((GP)gt, (LP)&s_cls[w][h][0], 16, 0, 0);  \
  }

  float res8[8];
  int   cls8[8];

  STAGE(0, 0)
#pragma unroll 1
  for (int j = 0; j < 8; ++j) {
    const int h = j & 1;
    if (j < 7) {
      STAGE(h ^ 1, j + 1)
      asm volatile("s_waitcnt vmcnt(9)" ::: "memory");
    } else {
      asm volatile("s_waitcnt vmcnt(0)" ::: "memory");
    }
    __builtin_amdgcn_sched_barrier(0);

    const int ci = s_cls[w][h][lane];
    const bool vld = (unsigned)ci < K_CLS;
    const int sc = vld ? ci : 0;
    float d2 = 0.f;
#pragma unroll
    for (int c = 0; c < C_CH; ++c) {
      const float x = s_buf[w][h][c][lane];
      const float d = s_ctr[c][sc] - x;
      d2 = fmaf(d, d, d2);
    }
    res8[j] = d2;
    cls8[j] = vld ? ci : -1;
  }

#pragma unroll
  for (int j = 0; j < 8; ++j) {
    if (cls8[j] >= 0) {
      const float r = sqrtf(res8[j] + EPSF) - THEA_F;
      if (r > 0.f) { atomAddF(&s_sq[cls8[j]], r * r); atomAddF(&s_pos[cls8[j]], 1.f); }
    }
  }

  __syncthreads();
  if (t < K_CLS) {
    float* vp = ws + OFF_VPART + (size_t)blockIdx.x * 64;
    vp[t]         = s_sq[t];
    vp[K_CLS + t] = s_pos[t];
  }
#undef STAGE
}

// ---- Finalize: reduce vparts, then loss_var + loss_dis + 0.001*loss_reg ---
__global__ __launch_bounds__(1024) void k_final(
    float* __restrict__ ws, float* __restrict__ out, int nb)
{
  __shared__ float s_ctr[C_CH * K_CLS];
  __shared__ float s_valid[K_CLS];
  __shared__ float s_sq[K_CLS];
  __shared__ float s_pos[K_CLS];
  __shared__ float s_red[3];
  __shared__ float s_ncls;
  const int t = threadIdx.x;
  if (t < 3) s_red[t] = 0.f;
  if (t < K_CLS) { s_sq[t] = 0.f; s_pos[t] = 0.f; }
  if (t < K_CLS) s_valid[t] = (ws[OFF_RED + C_CH * K_CLS + t] > MIN_PIX) ? 1.f : 0.f;
  for (int i = t; i < C_CH * K_CLS; i += 1024) {
    const int k = i % K_CLS;
    s_ctr[i] = ws[OFF_RED + i] / fmaxf(ws[OFF_RED + C_CH * K_CLS + k], 1.f);
  }
  __syncthreads();

  {
    const int o = t & 63, slice = t >> 6;
    if (o < 2 * K_CLS) {
      float a = 0.f;
      for (int b = slice; b < nb; b += 16)
        a += ws[OFF_VPART + (size_t)b * 64 + o];
      atomAddF(o < K_CLS ? &s_sq[o] : &s_pos[o - K_CLS], a);
    }
  }
  __syncthreads();

  if (t == 0) {
    float n = 0.f;
    for (int k = 0; k < K_CLS; ++k) n += s_valid[k];
    s_ncls = fmaxf(n, 1.f);
  }
  if (t < K_CLS && s_valid[t] > 0.f) {
    atomAddF(&s_red[0], s_sq[t] / fmaxf(s_pos[t], 1.f));
    float nn = 0.f;
#pragma unroll
    for (int ch = 0; ch < C_CH; ++ch) {
      const float cv = s_ctr[ch * K_CLS + t];
      nn = fmaf(cv, cv, nn);
    }
    atomAddF(&s_red[2], sqrtf(nn + EPSF));
  }
  if (t < K_CLS * K_CLS) {
    const int a = t / K_CLS, b = t - (t / K_CLS) * K_CLS;
    if (a != b && s_valid[a] > 0.f && s_valid[b] > 0.f) {
      float dd = 0.f;
#pragma unroll
      for (int ch = 0; ch < C_CH; ++ch) {
        const float df = s_ctr[ch * K_CLS + a] - s_ctr[ch * K_CLS + b];
        dd = fmaf(df, df, dd);
      }
      const float dist = sqrtf(dd + EPSF);
      const float d = fmaxf(TWO_DELTA - dist, 0.f);
      if (d > 0.f) atomAddF(&s_red[1], d * d);
    }
  }
  __syncthreads();
  if (t == 0) {
    const float n = s_ncls;
    out[0] = s_red[0] / n
           + s_red[1] / fmaxf(n * (n - 1.f), 1.f)
           + 0.001f * s_red[2] / n;
  }
}

extern "C" void kernel_launch(void* const* d_in, const int* in_sizes, int n_in,
                              void* d_out, int out_size, void* d_ws, size_t ws_size,
                              hipStream_t stream) {
  const float* pred = (const float*)d_in[0];
  const int*   tgt  = (const int*)d_in[1];
  float* ws  = (float*)d_ws;
  float* out = (float*)d_out;
  const int P = in_sizes[1];            // n*h*w = 2097152
  const int nBlocksVar = P / 2048;      // 1024

  k_accum <<<2048 + 64, 256, 0, stream>>>(pred, tgt, ws);  // 2048 sum + 64 count
  k_reduce<<<1, 256, 0, stream>>>(ws);
  k_var   <<<nBlocksVar, 256, 0, stream>>>(pred, tgt, ws);
  k_final <<<1, 1024, 0, stream>>>(ws, out, nBlocksVar);
}